// Round 7
// baseline (179.236 us; speedup 1.0000x reference)
//
#include <hip/hip_runtime.h>
#include <cstdint>
#include <cstddef>

// DigitCapsules routing: B=256, R=1152, C=10, IC=8, OC=16, 3 iters.
// R24 = R22 (proven 138.2 us) + final-squash folded into pass2 via the
// second-arrival pattern (saves 1 launch + 1 gap ~ 5.7 us):
//   pass2 block (b,sp): store partial -> threadfence (release, agent) ->
//   atomicAdd(cnt[b]) ACQ_REL/agent; second arrival (old==1) reloads both
//   partials with agent-scope atomic loads (bypass per-XCD L2, G16) and
//   writes squash -> out. cnt zeroed by u_s1 block 0 (stream-ordered).
// Recompute-u family (R18-R21,R23) closed: 3 structures, 3 different
// walls (scatter-latency / DS-pipe / LDS-staging+occupancy), all >=50
// us/pass vs 36 us for the coalesced u-read sweep.
//   L1 caps_u_s1: u bf16 (94 MB) + fused pass-0 partial -> part1 bf16;
//      zeroes cnt.
//   L2 caps_pass (pass1): prologue vsum=squash(0.1*sum part1); 9 sweeps;
//      partials -> p2a.  (s1_reduce folded, R22-proven)
//   L3 caps_pass (pass2): prologue folds vsum += squash(sum p2a); sweeps;
//      partials -> p2b; second-arrival block finalizes out. (NEW fold)
// Measured structural walls (prior sessions): pass u-read 2.6 TB/s
// logical ~83% of ~3.15 TB/s read ceiling (6 variants >= 36 us);
// caps_u_s1 pipe-sum ~44 us; cooperative fusion rejected by harness.
// Logits linear in v: b_t = u.(v1+..+v_{t-1}) -> running vsum, 1 pass/iter.
#define NB 256
#define NR 1152
#define NC 10
#define NI 8
#define NO 16
#define NSPLIT 2
#define NSWEEP 9     // r-sweeps per pass thread: 9*64 = 576 = NR/NSPLIT
#define NRC 144      // r-chunks in caps_u_s1 (8 r each)

static __device__ __forceinline__ uint32_t bf16_pack2(float lo, float hi) {
    uint32_t vl = __float_as_uint(lo);
    vl = vl + 0x7FFFu + ((vl >> 16) & 1u);
    uint32_t vh = __float_as_uint(hi);
    vh = vh + 0x7FFFu + ((vh >> 16) & 1u);
    return (vl >> 16) | (vh & 0xFFFF0000u);
}

// -------------------------------------------------------------------------
// caps_u_s1: 2304 blocks = 144 rc x 16 bg; 320 thr = c*32 + rl*4 + oq.
// W[r][c][i][oq*4..+3] = 8 float4 in regs; 16-deep b-loop; u-store uint2;
// fused s1 partial via rl-shuffle-reduce -> packed bf16 part1 (uint2).
// Block 0 also zeroes the 256 finalize counters (read by pass2 later in
// the stream -- inter-kernel ordering makes plain stores visible).
__global__ __launch_bounds__(320) void caps_u_s1_kernel(
    const float* __restrict__ x, const float* __restrict__ W,
    uint32_t* __restrict__ u, uint32_t* __restrict__ part1,
    uint32_t* __restrict__ cnt)
{
    const int t  = threadIdx.x;
    const int c  = t >> 5;             // 0..9
    const int rl = (t & 31) >> 2;      // 0..7
    const int oq = t & 3;              // 0..3
    const int rc = blockIdx.x >> 4;    // 0..143
    const int bg = blockIdx.x & 15;    // 0..15
    const int b0 = bg * 16;
    const int r  = rc * 8 + rl;

    if (blockIdx.x == 0 && t < NB) cnt[t] = 0u;

    __shared__ float xs[16][8][8];     // 4 KB

    if (t < 256) {                     // 256 float4 = x[b0..+16)[rc*8..+8)[8]
        const int bi = t >> 4, rem = t & 15;
        const int rr = rem >> 1, hf = rem & 1;
        *(float4*)&xs[bi][rr][hf * 4] =
            *(const float4*)(x + ((size_t)(b0 + bi) * NR + rc * 8 + rr) * 8 + hf * 4);
    }

    const float* wb = W + ((size_t)r * NC + c) * (NI * NO) + oq * 4;
    float4 wf[8];
#pragma unroll
    for (int i = 0; i < 8; ++i) wf[i] = *(const float4*)(wb + i * NO);

    __syncthreads();

#pragma unroll 2
    for (int bi = 0; bi < 16; ++bi) {
        const float4 xv4a = *(const float4*)&xs[bi][rl][0];
        const float4 xv4b = *(const float4*)&xs[bi][rl][4];
        const float xr[8] = {xv4a.x, xv4a.y, xv4a.z, xv4a.w,
                             xv4b.x, xv4b.y, xv4b.z, xv4b.w};
        float ax = 0.f, ay = 0.f, az = 0.f, aw = 0.f;
#pragma unroll
        for (int i = 0; i < 8; ++i) {
            const float xv = xr[i];
            ax = fmaf(xv, wf[i].x, ax); ay = fmaf(xv, wf[i].y, ay);
            az = fmaf(xv, wf[i].z, az); aw = fmaf(xv, wf[i].w, aw);
        }
        uint2 s;
        s.x = bf16_pack2(ax, ay);
        s.y = bf16_pack2(az, aw);
        *(uint2*)(u + (((size_t)(b0 + bi) * NC + c) * NR + r) * 8 + oq * 2) = s;

        // fused s1 partial: reduce fp32 quad over rl (lane bits 2..4)
        float sx = ax, sy = ay, sz = az, sw = aw;
#pragma unroll
        for (int off = 4; off <= 16; off <<= 1) {
            sx += __shfl_xor(sx, off); sy += __shfl_xor(sy, off);
            sz += __shfl_xor(sz, off); sw += __shfl_xor(sw, off);
        }
        if ((t & 28) == 0) {   // rl == 0 lanes: one uint2 per (bi,c,oq)
            uint2 p;
            p.x = bf16_pack2(sx, sy);
            p.y = bf16_pack2(sz, sw);
            *(uint2*)(part1 + ((size_t)(b0 + bi) * NRC + rc) * 80
                      + c * 8 + oq * 2) = p;
        }
    }
}

// -------------------------------------------------------------------------
// Routing pass: block = (b, sp), 256 thr = 64 rl x 4 oq, NSWEEP=9 sweeps.
// Prologue (pass1, part_prev==nullptr): vss = squash(0.1*sum of 144 bf16
//   part1 chunks) [s1_reduce folded]; also writes vsum.
// Prologue (pass2): vss = vsum + squash(sum of 2 fp32 part_prev).
// Main sweep -> partout [sp][b][160] fp32.
// Epilogue (pass2, outp != nullptr): second-arrival block per b reloads
// both partials coherently and writes squash -> outp.
__global__ __launch_bounds__(256, 2) void caps_pass_kernel(
    const uint32_t* __restrict__ u, const uint32_t* __restrict__ part1,
    float* __restrict__ vsum, const float* __restrict__ part_prev,
    float* partout, float* __restrict__ outp, uint32_t* cnt)
{
    const int b  = blockIdx.x >> 1;
    const int sp = blockIdx.x & 1;
    const int t  = threadIdx.x;
    const int oq = t & 3;
    const int rl = t >> 2;    // 0..63

    __shared__ float vss[160];
    __shared__ float sred[4][160];
    __shared__ uint32_t arrival;

    if (t < 160) {
        float v;
        if (part_prev != nullptr) {       // pass2: vsum + squash(s2)
            const float s = part_prev[(size_t)b * 160 + t]
                          + part_prev[((size_t)NB + b) * 160 + t];
            float n2 = s * s;
            n2 += __shfl_xor(n2, 1);
            n2 += __shfl_xor(n2, 2);
            n2 += __shfl_xor(n2, 4);
            n2 += __shfl_xor(n2, 8);
            const float nrm = sqrtf(n2);
            v = vsum[(size_t)b * 160 + t]
              + s * (n2 / (1.f + n2) / (nrm + 1e-8f));
        } else {                          // pass1: s1_reduce folded
            const uint32_t* p = part1 + (size_t)b * NRC * 80 + (t >> 1);
            const bool hi = t & 1;
            float s0 = 0.f, s1 = 0.f, s2 = 0.f, s3 = 0.f;
#pragma unroll 4
            for (int g = 0; g < NRC; g += 4) {
                const uint32_t w0 = p[(g + 0) * 80];
                const uint32_t w1 = p[(g + 1) * 80];
                const uint32_t w2 = p[(g + 2) * 80];
                const uint32_t w3 = p[(g + 3) * 80];
                s0 += hi ? __uint_as_float(w0 & 0xFFFF0000u) : __uint_as_float(w0 << 16);
                s1 += hi ? __uint_as_float(w1 & 0xFFFF0000u) : __uint_as_float(w1 << 16);
                s2 += hi ? __uint_as_float(w2 & 0xFFFF0000u) : __uint_as_float(w2 << 16);
                s3 += hi ? __uint_as_float(w3 & 0xFFFF0000u) : __uint_as_float(w3 << 16);
            }
            const float s = 0.1f * ((s0 + s1) + (s2 + s3));
            float n2 = s * s;
            n2 += __shfl_xor(n2, 1);
            n2 += __shfl_xor(n2, 2);
            n2 += __shfl_xor(n2, 4);
            n2 += __shfl_xor(n2, 8);
            const float nrm = sqrtf(n2);
            v = s * (n2 / (1.f + n2) / (nrm + 1e-8f));
            // both sp-blocks write identical bits — benign duplicate store
            vsum[(size_t)b * 160 + t] = v;
        }
        vss[t] = v;
    }
    __syncthreads();

    float acc[10][4];
#pragma unroll
    for (int c = 0; c < 10; ++c)
#pragma unroll
        for (int j = 0; j < 4; ++j) acc[c][j] = 0.f;

    const uint2* ub = (const uint2*)u + (size_t)b * NC * NR * 4 + oq;

    for (int k = 0; k < NSWEEP; ++k) {
        const int r = sp * (NSWEEP * 64) + k * 64 + rl;
        uint2 q[10];
#pragma unroll
        for (int c = 0; c < 10; ++c) q[c] = ub[((size_t)c * NR + r) * 4];

        float lg[10];
#pragma unroll
        for (int c = 0; c < 10; ++c) {
            const float4 vq = *(const float4*)&vss[c * 16 + oq * 4];
            float d = __uint_as_float(q[c].x << 16) * vq.x;
            d = fmaf(__uint_as_float(q[c].x & 0xFFFF0000u), vq.y, d);
            d = fmaf(__uint_as_float(q[c].y << 16),         vq.z, d);
            d = fmaf(__uint_as_float(q[c].y & 0xFFFF0000u), vq.w, d);
            lg[c] = d;
        }
#pragma unroll
        for (int c = 0; c < 10; ++c) {    // finish o-dot over 4 oq lanes
            lg[c] += __shfl_xor(lg[c], 1);
            lg[c] += __shfl_xor(lg[c], 2);
        }
        float m = lg[0];
#pragma unroll
        for (int c = 1; c < 10; ++c) m = fmaxf(m, lg[c]);
        float wgt[10], ssum = 0.f;
#pragma unroll
        for (int c = 0; c < 10; ++c) { wgt[c] = __expf(lg[c] - m); ssum += wgt[c]; }
        const float inv = 1.f / ssum;
#pragma unroll
        for (int c = 0; c < 10; ++c) {
            const float wv = wgt[c] * inv;
            acc[c][0] = fmaf(wv, __uint_as_float(q[c].x << 16),         acc[c][0]);
            acc[c][1] = fmaf(wv, __uint_as_float(q[c].x & 0xFFFF0000u), acc[c][1]);
            acc[c][2] = fmaf(wv, __uint_as_float(q[c].y << 16),         acc[c][2]);
            acc[c][3] = fmaf(wv, __uint_as_float(q[c].y & 0xFFFF0000u), acc[c][3]);
        }
    }

    // in-wave reduce over 16 rl-lanes (tid bits 2..5) — once per 9 r
#pragma unroll
    for (int off = 4; off <= 32; off <<= 1)
#pragma unroll
        for (int c = 0; c < 10; ++c)
#pragma unroll
            for (int j = 0; j < 4; ++j) acc[c][j] += __shfl_xor(acc[c][j], off);

    const int wv = t >> 6;
    if ((t & 63) < 4) {
#pragma unroll
        for (int c = 0; c < 10; ++c)
#pragma unroll
            for (int j = 0; j < 4; ++j)
                sred[wv][c * 16 + oq * 4 + j] = acc[c][j];
    }
    __syncthreads();

    if (t < 160) {
        partout[((size_t)sp * NB + b) * 160 + t]
            = sred[0][t] + sred[1][t] + sred[2][t] + sred[3][t];
    }

    if (outp != nullptr) {            // pass2: second-arrival finalize
        __threadfence();              // release our partial to agent scope
        if (t == 0)
            arrival = __hip_atomic_fetch_add(&cnt[b], 1u,
                          __ATOMIC_ACQ_REL, __HIP_MEMORY_SCOPE_AGENT);
        __syncthreads();
        if (arrival == 1u && t < 160) {
            const float s =
                  __hip_atomic_load(&partout[(size_t)b * 160 + t],
                      __ATOMIC_RELAXED, __HIP_MEMORY_SCOPE_AGENT)
                + __hip_atomic_load(&partout[((size_t)NB + b) * 160 + t],
                      __ATOMIC_RELAXED, __HIP_MEMORY_SCOPE_AGENT);
            float n2 = s * s;
            n2 += __shfl_xor(n2, 1);
            n2 += __shfl_xor(n2, 2);
            n2 += __shfl_xor(n2, 4);
            n2 += __shfl_xor(n2, 8);
            const float nrm   = sqrtf(n2);
            const float scale = n2 / (1.f + n2) / (nrm + 1e-8f);
            outp[(size_t)b * 160 + t] = scale * s;
        }
    }
}

// -------------------------------------------------------------------------
extern "C" void kernel_launch(void* const* d_in, const int* in_sizes, int n_in,
                              void* d_out, int out_size, void* d_ws, size_t ws_size,
                              hipStream_t stream) {
    const float* x = (const float*)d_in[0];   // [256,1152,8]
    const float* W = (const float*)d_in[1];   // [1,1152,10,8,16]
    float* out = (float*)d_out;               // [256,10,16]

    // ws: u 94,371,840 | part1 bf16 [256][144][80 u32] = 11,796,480
    //     p2a [2][256][160]f = 327,680 | p2b 327,680 | vsum 163,840
    //     cnt [256]u32 = 1,024
    uint8_t*  ws   = (uint8_t*)d_ws;
    uint32_t* u    = (uint32_t*)ws;
    uint32_t* prt1 = (uint32_t*)(ws + 94371840u);
    float*    p2a  = (float*)(ws + 94371840u + 11796480u);
    float*    p2b  = (float*)(ws + 94371840u + 11796480u + 327680u);
    float*    vsm  = (float*)(ws + 94371840u + 11796480u + 655360u);
    uint32_t* cnt  = (uint32_t*)(ws + 94371840u + 11796480u + 655360u + 163840u);

    caps_u_s1_kernel<<<2304, 320, 0, stream>>>(x, W, u, prt1, cnt);
    caps_pass_kernel<<<NB * NSPLIT, 256, 0, stream>>>(u, prt1, vsm, nullptr,
                                                      p2a, nullptr, cnt);
    caps_pass_kernel<<<NB * NSPLIT, 256, 0, stream>>>(u, nullptr, vsm, p2a,
                                                      p2b, out, cnt);
}

// Round 8
// 137.739 us; speedup vs baseline: 1.3013x; 1.3013x over previous
//
#include <hip/hip_runtime.h>
#include <cstdint>
#include <cstddef>

// DigitCapsules routing: B=256, R=1152, C=10, IC=8, OC=16, 3 iters.
// R25 = R22 VERBATIM REVERT (proven 138.24 us, session best).
// R24's second-arrival fold regressed BOTH passes 36-40 -> 61 us: the
// lost __restrict__ on partout + epilogue/fence code in the shared body
// degraded main-loop codegen (VALUBusy 20 -> 10%), not atomic traffic
// (FETCH unchanged). Closed directions, each with a measured mechanism:
//   - recompute-u (R18 scatter-latency / R19 DS-pipe / R21 occupancy-
//     insensitive latency / R23 LDS-staging+occupancy): all >=50 us/pass.
//   - cross-block final fold (R16 cooperative: harness rejects; R24
//     second-arrival: codegen regression on shared body).
// Ledger @138.2: u_s1 46 (write wall ~2.3 TB/s, pipe floor ~44), pass1
// ~40, pass2 ~36 (u-read pattern wall ~2.6 TB/s, 6 variants >= 36),
// 2 gaps ~8. Structural floor ~129 us; this kernel is within ~7%.
//   L1 caps_u_s1: u bf16 (94 MB) + fused pass-0 partial -> part1 bf16.
//   L2 caps_pass (pass1): prologue vsum=squash(0.1*sum part1); 9 uint2
//      sweeps; partials -> p2a.  (s1_reduce folded)
//   L3 caps_pass (pass2): prologue folds vsum += squash(sum p2a); -> p2b.
//   L4 caps_final: out = squash(sum p2b).
// Logits linear in v: b_t = u.(v1+..+v_{t-1}) -> running vsum, 1 pass/iter.
#define NB 256
#define NR 1152
#define NC 10
#define NI 8
#define NO 16
#define NSPLIT 2
#define NSWEEP 9     // r-sweeps per pass thread: 9*64 = 576 = NR/NSPLIT
#define NRC 144      // r-chunks in caps_u_s1 (8 r each)

static __device__ __forceinline__ uint32_t bf16_pack2(float lo, float hi) {
    uint32_t vl = __float_as_uint(lo);
    vl = vl + 0x7FFFu + ((vl >> 16) & 1u);
    uint32_t vh = __float_as_uint(hi);
    vh = vh + 0x7FFFu + ((vh >> 16) & 1u);
    return (vl >> 16) | (vh & 0xFFFF0000u);
}

// -------------------------------------------------------------------------
// caps_u_s1: 2304 blocks = 144 rc x 16 bg; 320 thr = c*32 + rl*4 + oq.
// W[r][c][i][oq*4..+3] = 8 float4 in regs; 16-deep b-loop; u-store uint2;
// fused s1 partial via rl-shuffle-reduce -> packed bf16 part1 (uint2).
__global__ __launch_bounds__(320) void caps_u_s1_kernel(
    const float* __restrict__ x, const float* __restrict__ W,
    uint32_t* __restrict__ u, uint32_t* __restrict__ part1)
{
    const int t  = threadIdx.x;
    const int c  = t >> 5;             // 0..9
    const int rl = (t & 31) >> 2;      // 0..7
    const int oq = t & 3;              // 0..3
    const int rc = blockIdx.x >> 4;    // 0..143
    const int bg = blockIdx.x & 15;    // 0..15
    const int b0 = bg * 16;
    const int r  = rc * 8 + rl;

    __shared__ float xs[16][8][8];     // 4 KB

    if (t < 256) {                     // 256 float4 = x[b0..+16)[rc*8..+8)[8]
        const int bi = t >> 4, rem = t & 15;
        const int rr = rem >> 1, hf = rem & 1;
        *(float4*)&xs[bi][rr][hf * 4] =
            *(const float4*)(x + ((size_t)(b0 + bi) * NR + rc * 8 + rr) * 8 + hf * 4);
    }

    const float* wb = W + ((size_t)r * NC + c) * (NI * NO) + oq * 4;
    float4 wf[8];
#pragma unroll
    for (int i = 0; i < 8; ++i) wf[i] = *(const float4*)(wb + i * NO);

    __syncthreads();

#pragma unroll 2
    for (int bi = 0; bi < 16; ++bi) {
        const float4 xv4a = *(const float4*)&xs[bi][rl][0];
        const float4 xv4b = *(const float4*)&xs[bi][rl][4];
        const float xr[8] = {xv4a.x, xv4a.y, xv4a.z, xv4a.w,
                             xv4b.x, xv4b.y, xv4b.z, xv4b.w};
        float ax = 0.f, ay = 0.f, az = 0.f, aw = 0.f;
#pragma unroll
        for (int i = 0; i < 8; ++i) {
            const float xv = xr[i];
            ax = fmaf(xv, wf[i].x, ax); ay = fmaf(xv, wf[i].y, ay);
            az = fmaf(xv, wf[i].z, az); aw = fmaf(xv, wf[i].w, aw);
        }
        uint2 s;
        s.x = bf16_pack2(ax, ay);
        s.y = bf16_pack2(az, aw);
        *(uint2*)(u + (((size_t)(b0 + bi) * NC + c) * NR + r) * 8 + oq * 2) = s;

        // fused s1 partial: reduce fp32 quad over rl (lane bits 2..4)
        float sx = ax, sy = ay, sz = az, sw = aw;
#pragma unroll
        for (int off = 4; off <= 16; off <<= 1) {
            sx += __shfl_xor(sx, off); sy += __shfl_xor(sy, off);
            sz += __shfl_xor(sz, off); sw += __shfl_xor(sw, off);
        }
        if ((t & 28) == 0) {   // rl == 0 lanes: one uint2 per (bi,c,oq)
            uint2 p;
            p.x = bf16_pack2(sx, sy);
            p.y = bf16_pack2(sz, sw);
            *(uint2*)(part1 + ((size_t)(b0 + bi) * NRC + rc) * 80
                      + c * 8 + oq * 2) = p;
        }
    }
}

// -------------------------------------------------------------------------
// Routing pass (R8/R12 proven main loop): block = (b, sp), 256 thr =
// 64 rl x 4 oq, NSWEEP=9 sweeps of uint2.
// Prologue (pass1, part_prev==nullptr): vss = squash(0.1*sum of 144 bf16
//   part1 chunks) [s1_reduce folded, verbatim loop]; also writes vsum.
// Prologue (pass2): vss = vsum + squash(sum of 2 fp32 part_prev).
// Main sweep -> partout [sp][b][160] fp32.
__global__ __launch_bounds__(256, 2) void caps_pass_kernel(
    const uint32_t* __restrict__ u, const uint32_t* __restrict__ part1,
    float* __restrict__ vsum, const float* __restrict__ part_prev,
    float* __restrict__ partout)
{
    const int b  = blockIdx.x >> 1;
    const int sp = blockIdx.x & 1;
    const int t  = threadIdx.x;
    const int oq = t & 3;
    const int rl = t >> 2;    // 0..63

    __shared__ float vss[160];
    __shared__ float sred[4][160];

    if (t < 160) {
        float v;
        if (part_prev != nullptr) {       // pass2: vsum + squash(s2)
            const float s = part_prev[(size_t)b * 160 + t]
                          + part_prev[((size_t)NB + b) * 160 + t];
            float n2 = s * s;
            n2 += __shfl_xor(n2, 1);
            n2 += __shfl_xor(n2, 2);
            n2 += __shfl_xor(n2, 4);
            n2 += __shfl_xor(n2, 8);
            const float nrm = sqrtf(n2);
            v = vsum[(size_t)b * 160 + t]
              + s * (n2 / (1.f + n2) / (nrm + 1e-8f));
        } else {                          // pass1: s1_reduce folded
            const uint32_t* p = part1 + (size_t)b * NRC * 80 + (t >> 1);
            const bool hi = t & 1;
            float s0 = 0.f, s1 = 0.f, s2 = 0.f, s3 = 0.f;
#pragma unroll 4
            for (int g = 0; g < NRC; g += 4) {
                const uint32_t w0 = p[(g + 0) * 80];
                const uint32_t w1 = p[(g + 1) * 80];
                const uint32_t w2 = p[(g + 2) * 80];
                const uint32_t w3 = p[(g + 3) * 80];
                s0 += hi ? __uint_as_float(w0 & 0xFFFF0000u) : __uint_as_float(w0 << 16);
                s1 += hi ? __uint_as_float(w1 & 0xFFFF0000u) : __uint_as_float(w1 << 16);
                s2 += hi ? __uint_as_float(w2 & 0xFFFF0000u) : __uint_as_float(w2 << 16);
                s3 += hi ? __uint_as_float(w3 & 0xFFFF0000u) : __uint_as_float(w3 << 16);
            }
            const float s = 0.1f * ((s0 + s1) + (s2 + s3));
            float n2 = s * s;
            n2 += __shfl_xor(n2, 1);
            n2 += __shfl_xor(n2, 2);
            n2 += __shfl_xor(n2, 4);
            n2 += __shfl_xor(n2, 8);
            const float nrm = sqrtf(n2);
            v = s * (n2 / (1.f + n2) / (nrm + 1e-8f));
            // both sp-blocks write identical bits (same inputs/code) —
            // benign duplicate store; pass2 reads it next launch.
            vsum[(size_t)b * 160 + t] = v;
        }
        vss[t] = v;
    }
    __syncthreads();

    float acc[10][4];
#pragma unroll
    for (int c = 0; c < 10; ++c)
#pragma unroll
        for (int j = 0; j < 4; ++j) acc[c][j] = 0.f;

    const uint2* ub = (const uint2*)u + (size_t)b * NC * NR * 4 + oq;

    for (int k = 0; k < NSWEEP; ++k) {
        const int r = sp * (NSWEEP * 64) + k * 64 + rl;
        uint2 q[10];
#pragma unroll
        for (int c = 0; c < 10; ++c) q[c] = ub[((size_t)c * NR + r) * 4];

        float lg[10];
#pragma unroll
        for (int c = 0; c < 10; ++c) {
            const float4 vq = *(const float4*)&vss[c * 16 + oq * 4];
            float d = __uint_as_float(q[c].x << 16) * vq.x;
            d = fmaf(__uint_as_float(q[c].x & 0xFFFF0000u), vq.y, d);
            d = fmaf(__uint_as_float(q[c].y << 16),         vq.z, d);
            d = fmaf(__uint_as_float(q[c].y & 0xFFFF0000u), vq.w, d);
            lg[c] = d;
        }
#pragma unroll
        for (int c = 0; c < 10; ++c) {    // finish o-dot over 4 oq lanes
            lg[c] += __shfl_xor(lg[c], 1);
            lg[c] += __shfl_xor(lg[c], 2);
        }
        float m = lg[0];
#pragma unroll
        for (int c = 1; c < 10; ++c) m = fmaxf(m, lg[c]);
        float wgt[10], ssum = 0.f;
#pragma unroll
        for (int c = 0; c < 10; ++c) { wgt[c] = __expf(lg[c] - m); ssum += wgt[c]; }
        const float inv = 1.f / ssum;
#pragma unroll
        for (int c = 0; c < 10; ++c) {
            const float wv = wgt[c] * inv;
            acc[c][0] = fmaf(wv, __uint_as_float(q[c].x << 16),         acc[c][0]);
            acc[c][1] = fmaf(wv, __uint_as_float(q[c].x & 0xFFFF0000u), acc[c][1]);
            acc[c][2] = fmaf(wv, __uint_as_float(q[c].y << 16),         acc[c][2]);
            acc[c][3] = fmaf(wv, __uint_as_float(q[c].y & 0xFFFF0000u), acc[c][3]);
        }
    }

    // in-wave reduce over 16 rl-lanes (tid bits 2..5) — once per 9 r
#pragma unroll
    for (int off = 4; off <= 32; off <<= 1)
#pragma unroll
        for (int c = 0; c < 10; ++c)
#pragma unroll
            for (int j = 0; j < 4; ++j) acc[c][j] += __shfl_xor(acc[c][j], off);

    const int wv = t >> 6;
    if ((t & 63) < 4) {
#pragma unroll
        for (int c = 0; c < 10; ++c)
#pragma unroll
            for (int j = 0; j < 4; ++j)
                sred[wv][c * 16 + oq * 4 + j] = acc[c][j];
    }
    __syncthreads();

    if (t < 160) {
        partout[((size_t)sp * NB + b) * 160 + t]
            = sred[0][t] + sred[1][t] + sred[2][t] + sred[3][t];
    }
}

// -------------------------------------------------------------------------
// final: out = squash(sum of 2 partials). grid=256 (b), 192 thr.
__global__ __launch_bounds__(192) void caps_final_kernel(
    const float* __restrict__ p2b, float* __restrict__ out)
{
    const int b = blockIdx.x;
    const int t = threadIdx.x;
    if (t >= 160) return;
    const float s = p2b[(size_t)b * 160 + t]
                  + p2b[((size_t)NB + b) * 160 + t];
    float n2 = s * s;
    n2 += __shfl_xor(n2, 1);
    n2 += __shfl_xor(n2, 2);
    n2 += __shfl_xor(n2, 4);
    n2 += __shfl_xor(n2, 8);
    const float nrm   = sqrtf(n2);
    const float scale = n2 / (1.f + n2) / (nrm + 1e-8f);
    out[(size_t)b * 160 + t] = scale * s;
}

// -------------------------------------------------------------------------
extern "C" void kernel_launch(void* const* d_in, const int* in_sizes, int n_in,
                              void* d_out, int out_size, void* d_ws, size_t ws_size,
                              hipStream_t stream) {
    const float* x = (const float*)d_in[0];   // [256,1152,8]
    const float* W = (const float*)d_in[1];   // [1,1152,10,8,16]
    float* out = (float*)d_out;               // [256,10,16]

    // ws: u 94,371,840 | part1 bf16 [256][144][80 u32] = 11,796,480
    //     p2a [2][256][160]f = 327,680 | p2b 327,680 | vsum 163,840
    uint8_t*  ws   = (uint8_t*)d_ws;
    uint32_t* u    = (uint32_t*)ws;
    uint32_t* prt1 = (uint32_t*)(ws + 94371840u);
    float*    p2a  = (float*)(ws + 94371840u + 11796480u);
    float*    p2b  = (float*)(ws + 94371840u + 11796480u + 327680u);
    float*    vsm  = (float*)(ws + 94371840u + 11796480u + 655360u);

    caps_u_s1_kernel<<<2304, 320, 0, stream>>>(x, W, u, prt1);
    caps_pass_kernel<<<NB * NSPLIT, 256, 0, stream>>>(u, prt1, vsm, nullptr, p2a);
    caps_pass_kernel<<<NB * NSPLIT, 256, 0, stream>>>(u, nullptr, vsm, p2a, p2b);
    caps_final_kernel<<<NB, 192, 0, stream>>>(p2b, out);
}